// Round 2
// baseline (9.723 us; speedup 1.0000x reference)
//
#include <hip/hip_runtime.h>

// Reference semantics (faithful to the degenerate source):
//   M = 250, SQ = 12, N_REGIONS = 10, all region starts = (0,0).
//   S[b] = sum of u[b, 0:12, 0:12]^2
//   out[b, r] = S[b] / sqrt(10 * S[b]^2)   for r in 0..9
//
// Only the 12x12 top-left patch of each slice is read: ~2.4 MB total.
// Launch-overhead bound; this round: 4 waves/block (grid 1024, was 4096)
// and float2 loads (rows are 8B-aligned: stride 1000 B).

#define MDIM 250
#define SQ 12
#define NREG 10
#define F2_PER_PATCH 72  // 12 rows * 6 float2

__global__ __launch_bounds__(256) void imaging_layer_kernel(
    const float* __restrict__ u, float* __restrict__ out, int batch) {
    const int wave = threadIdx.x >> 6;  // 0..3
    const int lane = threadIdx.x & 63;
    const int b = blockIdx.x * 4 + wave;
    if (b >= batch) return;

    const float* ub = u + (size_t)b * (MDIM * MDIM);

    float s = 0.0f;

    // i = lane (all 64 lanes, i < 72 always true)
    {
        const int i = lane;
        const int r = i / 6;
        const int c = (i - r * 6) * 2;
        const float2 v = *(const float2*)(ub + r * MDIM + c);
        s += v.x * v.x + v.y * v.y;
    }
    // i = 64 + lane (only lanes 0..7)
    {
        const int i = 64 + lane;
        if (i < F2_PER_PATCH) {
            const int r = i / 6;
            const int c = (i - r * 6) * 2;
            const float2 v = *(const float2*)(ub + r * MDIM + c);
            s += v.x * v.x + v.y * v.y;
        }
    }

    // Wave-wide butterfly reduction across all 64 lanes.
#pragma unroll
    for (int off = 32; off > 0; off >>= 1) {
        s += __shfl_xor(s, off, 64);
    }

    const float val = s / sqrtf(10.0f * s * s);

    if (lane < NREG) {
        out[(size_t)b * NREG + lane] = val;
    }
}

extern "C" void kernel_launch(void* const* d_in, const int* in_sizes, int n_in,
                              void* d_out, int out_size, void* d_ws, size_t ws_size,
                              hipStream_t stream) {
    const float* u = (const float*)d_in[0];
    float* out = (float*)d_out;

    const int batch = in_sizes[0] / (MDIM * MDIM);  // 4096
    const int grid = (batch + 3) / 4;               // 1024

    imaging_layer_kernel<<<grid, 256, 0, stream>>>(u, out, batch);
}